// Round 3
// baseline (59.471 us; speedup 1.0000x reference)
//
#include <hip/hip_runtime.h>

#define B_ 16
#define U_ 500
#define S_ 256
#define H_ 128
#define UTILE 16
#define NWAVES 16
#define TPB (NWAVES * 64)
#define HHALF 64

__global__ __launch_bounds__(TPB, 8) void attn_kernel(
    const float* __restrict__ user,     // (B,U,4)
    const float* __restrict__ server,   // (B,S,6)
    const int*   __restrict__ masks,    // (B,U,S) int32 0/1 OR packed bytes (auto-detected)
    const float* __restrict__ Wu,       // (3,H)
    const float* __restrict__ bu,       // (H)
    const float* __restrict__ Ws,       // (7,H)  (row 6 multiplies the zero 'active' col -> unused)
    const float* __restrict__ bs,       // (H)
    const float* __restrict__ W1,       // (H,H)
    const float* __restrict__ W2,       // (H,H)
    const float* __restrict__ vt,       // (H)
    float* __restrict__ out)            // (B,U,S) fp32
{
  // 2 blocks/CU requires <= 80 KB LDS: E holds only 64 of 128 h-rows; two passes.
  __shared__ float E[HHALF][S_];       // 64 KB, [h_local][s], exp(2*enc)
  __shared__ float M1s[6 * H_];        // Ws@W1 (rows 0..5)           3 KB
  __shared__ float M2s[3 * H_];        // Wu@W2                       1.5 KB
  __shared__ float c1s[H_];            // bs@W1
  __shared__ float c2s[H_];            // bu@W2
  __shared__ float decs[8][2][HHALF];  // exp(2*dec), this pass's h   4 KB
  __shared__ float redmax[8][2][2];    // cross-s-half softmax partials
  __shared__ float redsum[8][2][2];
  __shared__ float vsum_s;

  const int tid = threadIdx.x;
  const int bid = blockIdx.x;
  const int b   = bid >> 5;            // 32 u-tiles per b
  const int u0  = (bid & 31) * UTILE;

  // ---- phase 0: fused weight products (redundant per block, negligible) ----
  {
    const int h = tid & (H_ - 1);
    for (int job = tid >> 7; job < 11; job += 8) {
      const float* Lv; const float* Rm; float* dst;
      if (job < 6)       { Lv = Ws + job * H_;       Rm = W1; dst = M1s + job * H_; }
      else if (job == 6) { Lv = bs;                  Rm = W1; dst = c1s; }
      else if (job < 10) { Lv = Wu + (job - 7) * H_; Rm = W2; dst = M2s + (job - 7) * H_; }
      else               { Lv = bu;                  Rm = W2; dst = c2s; }
      float acc = 0.f;
      for (int j = 0; j < H_; ++j) acc = fmaf(Lv[j], Rm[j * H_ + h], acc);
      dst[h] = acc;
    }
    if (tid < 64) {                       // vsum = sum(vt), from global (no LDS dep)
      float v = vt[tid] + vt[tid + 64];
      #pragma unroll
      for (int off = 32; off > 0; off >>= 1) v += __shfl_xor(v, off, 64);
      if (tid == 0) vsum_s = v;
    }
  }

  // ---- mask dtype detection: int32 masks are strictly 0/1; packed bools make words >1 ----
  int lflag;
  {
    int4 mw = *reinterpret_cast<const int4*>(masks + tid * 4);   // first 16 KB, in-bounds either way
    lflag = ((unsigned)mw.x > 1u) | ((unsigned)mw.y > 1u) |
            ((unsigned)mw.z > 1u) | ((unsigned)mw.w > 1u);
  }
  const int bytemode = __syncthreads_or(lflag);   // barrier also publishes phase-0 LDS

  // wave decomposition: wave = (row-group rg, s-half sh); lane owns 2 s for 2 u-rows
  const int w    = tid >> 6;
  const int lane = tid & 63;
  const int rg   = w >> 1;              // 0..7 -> u-rows u0+2*rg, u0+2*rg+1
  const int sh   = w & 1;               // 0/1  -> s in [sh*128, sh*128+128)
  const int s0   = sh * 128 + 2 * lane;

  size_t ridx[2]; int uval[2]; int m0[2], m1[2];
  #pragma unroll
  for (int r = 0; r < 2; ++r) {
    const int u = u0 + rg * 2 + r;
    uval[r] = (u < U_);
    ridx[r] = ((size_t)b * U_ + min(u, U_ - 1)) * S_ + s0;
  }

  // this wave stages dec row r=sh of its group: keep user features in regs
  const int uStage = min(u0 + rg * 2 + sh, U_ - 1);
  const float* uv = user + ((size_t)b * U_ + uStage) * 4;
  const float g0 = uv[0], g1 = uv[1], g2 = uv[2];

  // server features for this thread's staging column (reloaded per pass, L1-hot)
  const int   sStage = tid & (S_ - 1);
  const int   h0     = tid >> 8;        // 0..3, wave-uniform
  const float2* sv = reinterpret_cast<const float2*>(server + ((size_t)b * S_ + sStage) * 6);

  float acc[2][2] = {{0.f, 0.f}, {0.f, 0.f}};   // [row][s]  carried across both h-passes

  auto quad = [](const float4& vv, float ea, float eb, float ec, float ed,
                 const float4& d, float& a) {
    float t0 = fmaf(ea, d.x, 1.0f);
    float t1 = fmaf(eb, d.y, 1.0f);
    float t2 = fmaf(ec, d.z, 1.0f);
    float t3 = fmaf(ed, d.w, 1.0f);
    float t01 = t0 * t1;
    float t23 = t2 * t3;
    float n01 = fmaf(vv.x, t1, vv.y * t0);
    float n23 = fmaf(vv.z, t3, vv.w * t2);
    float den = t01 * t23;
    float num = fmaf(n01, t23, n23 * t01);
    a = fmaf(num, __builtin_amdgcn_rcpf(den), a);
  };

  #pragma unroll 1
  for (int pass = 0; pass < 2; ++pass) {
    const int hbase = pass * HHALF;

    // ---- stage E[hr][s] = exp(2*(c1[h] + server.M1[h])) for h = hbase+hr ----
    {
      const float2 p0 = sv[0], p1 = sv[1], p2 = sv[2];
      for (int hr = h0; hr < HHALF; hr += 4) {
        const int h = hbase + hr;
        float a = c1s[h];
        a = fmaf(p0.x, M1s[0 * H_ + h], a);
        a = fmaf(p0.y, M1s[1 * H_ + h], a);
        a = fmaf(p1.x, M1s[2 * H_ + h], a);
        a = fmaf(p1.y, M1s[3 * H_ + h], a);
        a = fmaf(p2.x, M1s[4 * H_ + h], a);
        a = fmaf(p2.y, M1s[5 * H_ + h], a);
        E[hr][sStage] = __expf(fminf(fmaxf(a + a, -60.f), 60.f));
      }
    }
    // ---- stage this wave's dec row (r = sh), h = hbase + lane ----
    {
      const int h = hbase + lane;
      float a = c2s[h];
      a = fmaf(g0, M2s[0 * H_ + h], a);
      a = fmaf(g1, M2s[1 * H_ + h], a);
      a = fmaf(g2, M2s[2 * H_ + h], a);
      decs[rg][sh][lane] = __expf(fminf(fmaxf(a + a, -60.f), 60.f));
    }
    __syncthreads();   // E + decs visible

    // ---- issue mask loads on pass 0; HBM latency hides under pass-0 compute ----
    if (pass == 0) {
      if (!bytemode) {
        #pragma unroll
        for (int r = 0; r < 2; ++r) {
          int2 mm = *reinterpret_cast<const int2*>(masks + ridx[r]);
          m0[r] = mm.x; m1[r] = mm.y;
        }
      } else {
        const unsigned char* mb = reinterpret_cast<const unsigned char*>(masks);
        #pragma unroll
        for (int r = 0; r < 2; ++r) {
          uchar2 mm = *reinterpret_cast<const uchar2*>(mb + ridx[r]);
          m0[r] = mm.x; m1[r] = mm.y;
        }
      }
    }

    // ---- accumulate: acc[r][j] += sum_h v_h / (E_h*D_h + 1), 4 h per quad, one rcp ----
    #pragma unroll 4
    for (int h4 = 0; h4 < HHALF / 4; ++h4) {
      const int hh = h4 * 4;
      const float2 e0 = *reinterpret_cast<const float2*>(&E[hh + 0][s0]);
      const float2 e1 = *reinterpret_cast<const float2*>(&E[hh + 1][s0]);
      const float2 e2 = *reinterpret_cast<const float2*>(&E[hh + 2][s0]);
      const float2 e3 = *reinterpret_cast<const float2*>(&E[hh + 3][s0]);
      const float4 d0 = *reinterpret_cast<const float4*>(&decs[rg][0][hh]);  // LDS broadcast
      const float4 d1 = *reinterpret_cast<const float4*>(&decs[rg][1][hh]);  // LDS broadcast
      const float4 vv = *reinterpret_cast<const float4*>(vt + hbase + hh);   // uniform scalar load
      quad(vv, e0.x, e1.x, e2.x, e3.x, d0, acc[0][0]);
      quad(vv, e0.y, e1.y, e2.y, e3.y, d0, acc[0][1]);
      quad(vv, e0.x, e1.x, e2.x, e3.x, d1, acc[1][0]);
      quad(vv, e0.y, e1.y, e2.y, e3.y, d1, acc[1][1]);
    }
    __syncthreads();   // all reads of E done before next pass overwrites / epilogue LDS reuse
  }

  // ---- mask + cross-wave-pair softmax + store ----
  const float negs = -103.6163291847321f * 10.0f;   // log(1e-45) * EXPLORATION_C
  const float vs10 = vsum_s * 10.0f;
  float p[2][2];
  #pragma unroll
  for (int r = 0; r < 2; ++r) {
    float sA = m0[r] ? fmaf(-20.0f, acc[r][0], vs10) : negs;
    float sB = m1[r] ? fmaf(-20.0f, acc[r][1], vs10) : negs;
    p[r][0] = sA; p[r][1] = sB;
    float mx = fmaxf(sA, sB);
    #pragma unroll
    for (int off = 32; off > 0; off >>= 1) mx = fmaxf(mx, __shfl_xor(mx, off, 64));
    if (lane == 0) redmax[rg][r][sh] = mx;
  }
  __syncthreads();
  #pragma unroll
  for (int r = 0; r < 2; ++r) {
    const float gmx = fmaxf(redmax[rg][r][0], redmax[rg][r][1]);
    float pa = __expf(p[r][0] - gmx);
    float pb = __expf(p[r][1] - gmx);
    p[r][0] = pa; p[r][1] = pb;
    float sm = pa + pb;
    #pragma unroll
    for (int off = 32; off > 0; off >>= 1) sm += __shfl_xor(sm, off, 64);
    if (lane == 0) redsum[rg][r][sh] = sm;
  }
  __syncthreads();
  #pragma unroll
  for (int r = 0; r < 2; ++r) {
    if (uval[r]) {
      const float inv = __builtin_amdgcn_rcpf(redsum[rg][r][0] + redsum[rg][r][1]);
      float2 o; o.x = p[r][0] * inv; o.y = p[r][1] * inv;
      *reinterpret_cast<float2*>(out + ridx[r]) = o;
    }
  }
}

extern "C" void kernel_launch(void* const* d_in, const int* in_sizes, int n_in,
                              void* d_out, int out_size, void* d_ws, size_t ws_size,
                              hipStream_t stream) {
  const float* user   = (const float*)d_in[0];
  const float* server = (const float*)d_in[1];
  const int*   masks  = (const int*)d_in[2];
  const float* Wu = (const float*)d_in[3];
  const float* bu = (const float*)d_in[4];
  const float* Ws = (const float*)d_in[5];
  const float* bs = (const float*)d_in[6];
  const float* W1 = (const float*)d_in[7];
  const float* W2 = (const float*)d_in[8];
  const float* vt = (const float*)d_in[9];
  float* out = (float*)d_out;
  (void)in_sizes; (void)n_in; (void)out_size; (void)d_ws; (void)ws_size;

  attn_kernel<<<dim3(B_ * ((U_ + UTILE - 1) / UTILE)), dim3(TPB), 0, stream>>>(
      user, server, masks, Wu, bu, Ws, bs, W1, W2, vt, out);
}

// Round 4
// 45.499 us; speedup vs baseline: 1.3071x; 1.3071x over previous
//
#include <hip/hip_runtime.h>

#define B_ 16
#define U_ 500
#define S_ 256
#define H_ 128
#define UTILE 32
#define NWAVES 16
#define TPB (NWAVES * 64)

__global__ __launch_bounds__(TPB, 1) void attn_kernel(
    const float* __restrict__ user,     // (B,U,4)
    const float* __restrict__ server,   // (B,S,6)
    const int*   __restrict__ masks,    // (B,U,S) int32 0/1 OR packed bytes (auto-detected)
    const float* __restrict__ Wu,       // (3,H)
    const float* __restrict__ bu,       // (H)
    const float* __restrict__ Ws,       // (7,H)  (row 6 multiplies the zero 'active' col -> unused)
    const float* __restrict__ bs,       // (H)
    const float* __restrict__ W1,       // (H,H)
    const float* __restrict__ W2,       // (H,H)
    const float* __restrict__ vt,       // (H)
    float* __restrict__ out)            // (B,U,S) fp32
{
  __shared__ float E[H_][S_];          // 128 KB, transposed [h][s], holds exp(2*enc)
  __shared__ float M1s[6 * H_];        // Ws@W1 (rows 0..5)
  __shared__ float M2s[3 * H_];        // Wu@W2
  __shared__ float c1s[H_];            // bs@W1
  __shared__ float c2s[H_];            // bu@W2
  __shared__ float vts[H_];
  __shared__ float decs[NWAVES][2][H_]; // exp(2*dec) for each wave's two u-rows
  __shared__ float vsum_s;

  const int tid = threadIdx.x;
  const int bid = blockIdx.x;
  const int b   = bid >> 4;
  const int u0  = (bid & 15) * UTILE;

  // ---- phase 0: fused weight products (redundant per block, negligible) ----
  {
    const int h = tid & (H_ - 1);
    for (int job = tid >> 7; job < 11; job += 8) {
      const float* Lv; const float* Rm; float* dst;
      if (job < 6)       { Lv = Ws + job * H_;       Rm = W1; dst = M1s + job * H_; }
      else if (job == 6) { Lv = bs;                  Rm = W1; dst = c1s; }
      else if (job < 10) { Lv = Wu + (job - 7) * H_; Rm = W2; dst = M2s + (job - 7) * H_; }
      else               { Lv = bu;                  Rm = W2; dst = c2s; }
      float acc = 0.f;
      for (int j = 0; j < H_; ++j) acc = fmaf(Lv[j], Rm[j * H_ + h], acc);
      dst[h] = acc;
    }
    if (tid < H_) vts[tid] = vt[tid];
    if (tid < 64) {                       // vsum = sum(vt), from global (no LDS dep)
      float v = vt[tid] + vt[tid + 64];
      #pragma unroll
      for (int off = 32; off > 0; off >>= 1) v += __shfl_xor(v, off, 64);
      if (tid == 0) vsum_s = v;
    }
  }

  // ---- mask dtype detection: int32 masks are strictly 0/1; packed bools make words >1 ----
  int lflag;
  {
    int4 mw = *reinterpret_cast<const int4*>(masks + tid * 4);   // first 4096 words, in-bounds either way
    lflag = ((unsigned)mw.x > 1u) | ((unsigned)mw.y > 1u) |
            ((unsigned)mw.z > 1u) | ((unsigned)mw.w > 1u);
  }
  const int bytemode = __syncthreads_or(lflag);   // barrier also publishes phase-0 LDS

  // ---- phase 1: stage E[h][s] = exp(2*(c1[h] + sum_k server[b,s,k]*M1[k][h])) ----
  {
    const int s  = tid & (S_ - 1);
    const int h0 = tid >> 8;   // 0..3, wave-uniform
    const float2* sv = reinterpret_cast<const float2*>(server + ((size_t)b * S_ + s) * 6);
    const float2 p0 = sv[0], p1 = sv[1], p2 = sv[2];
    for (int h = h0; h < H_; h += 4) {
      float a = c1s[h];
      a = fmaf(p0.x, M1s[0 * H_ + h], a);
      a = fmaf(p0.y, M1s[1 * H_ + h], a);
      a = fmaf(p1.x, M1s[2 * H_ + h], a);
      a = fmaf(p1.y, M1s[3 * H_ + h], a);
      a = fmaf(p2.x, M1s[4 * H_ + h], a);
      a = fmaf(p2.y, M1s[5 * H_ + h], a);
      E[h][s] = __expf(fminf(fmaxf(a + a, -60.f), 60.f));
    }
  }

  const int w    = tid >> 6;
  const int lane = tid & 63;
  const int uA   = u0 + 2 * w;          // pairs are both-valid or both-invalid (U_ even, u0 even)
  const int uAc  = min(uA,     U_ - 1);
  const int uBc  = min(uA + 1, U_ - 1);

  // ---- dec rows for both u's: D = exp(2*dec). Same-wave LDS slot, no barrier needed for decs. ----
  {
    const float* uvA = user + ((size_t)b * U_ + uAc) * 4;
    const float* uvB = user + ((size_t)b * U_ + uBc) * 4;
    const float gA0 = uvA[0], gA1 = uvA[1], gA2 = uvA[2];
    const float gB0 = uvB[0], gB1 = uvB[1], gB2 = uvB[2];
    #pragma unroll
    for (int r = 0; r < 2; ++r) {
      const int h1 = lane, h2 = lane + 64;
      const float g0 = r ? gB0 : gA0, g1 = r ? gB1 : gA1, g2 = r ? gB2 : gA2;
      float a0 = c2s[h1];
      a0 = fmaf(g0, M2s[0 * H_ + h1], a0);
      a0 = fmaf(g1, M2s[1 * H_ + h1], a0);
      a0 = fmaf(g2, M2s[2 * H_ + h1], a0);
      decs[w][r][h1] = __expf(fminf(fmaxf(a0 + a0, -60.f), 60.f));
      float a1 = c2s[h2];
      a1 = fmaf(g0, M2s[0 * H_ + h2], a1);
      a1 = fmaf(g1, M2s[1 * H_ + h2], a1);
      a1 = fmaf(g2, M2s[2 * H_ + h2], a1);
      decs[w][r][h2] = __expf(fminf(fmaxf(a1 + a1, -60.f), 60.f));
    }
  }
  __syncthreads();   // publishes E (decs is same-wave, also covered)

  // ---- issue mask loads early to hide HBM latency under the h4 loop ----
  const size_t ridxA = ((size_t)b * U_ + uAc) * S_ + (size_t)lane * 4;
  const size_t ridxB = ((size_t)b * U_ + uBc) * S_ + (size_t)lane * 4;
  int mA0, mA1, mA2, mA3, mB0, mB1, mB2, mB3;
  if (!bytemode) {
    int4 mm = *reinterpret_cast<const int4*>(masks + ridxA);
    mA0 = mm.x; mA1 = mm.y; mA2 = mm.z; mA3 = mm.w;
    int4 nn = *reinterpret_cast<const int4*>(masks + ridxB);
    mB0 = nn.x; mB1 = nn.y; mB2 = nn.z; mB3 = nn.w;
  } else {
    const unsigned char* mb = reinterpret_cast<const unsigned char*>(masks);
    uchar4 mm = *reinterpret_cast<const uchar4*>(mb + ridxA);
    mA0 = mm.x; mA1 = mm.y; mA2 = mm.z; mA3 = mm.w;
    uchar4 nn = *reinterpret_cast<const uchar4*>(mb + ridxB);
    mB0 = nn.x; mB1 = nn.y; mB2 = nn.z; mB3 = nn.w;
  }

  // ---- wave skew: desynchronize the 4 waves on each SIMD so their LDS bursts
  // and VALU bursts interleave instead of phase-locking at ~50% duty.
  // One-time dependent-FMA delay chain, length ~0..450 cycles across waves.
  // (No barrier exists in the main loop, so the offset persists to the end.)
  {
    const int skew = ((w >> 2) * 24) + ((w & 3) * 6);
    float z = vsum_s;
    for (int i = 0; i < skew; ++i) z = fmaf(z, 0.9999999f, 1e-30f);
    asm volatile("" :: "v"(z));   // keep the chain live (rule #17)
  }

  // ---- main accumulation: lane l owns s = 4l..4l+3 for BOTH u-rows in one E pass ----
  // acc = sum_h v_h / (E_h*D_h + 1), computed 4 h at a time with ONE rcp:
  //   sum v_i/t_i = ((v0 t1 + v1 t0) t2 t3 + (v2 t3 + v3 t2) t0 t1) / (t0 t1 t2 t3)
  float aA0 = 0.f, aA1 = 0.f, aA2 = 0.f, aA3 = 0.f;
  float aB0 = 0.f, aB1 = 0.f, aB2 = 0.f, aB3 = 0.f;
  #pragma unroll 4
  for (int h4 = 0; h4 < H_ / 4; ++h4) {
    const float4 e0 = *reinterpret_cast<const float4*>(&E[h4 * 4 + 0][lane * 4]);
    const float4 e1 = *reinterpret_cast<const float4*>(&E[h4 * 4 + 1][lane * 4]);
    const float4 e2 = *reinterpret_cast<const float4*>(&E[h4 * 4 + 2][lane * 4]);
    const float4 e3 = *reinterpret_cast<const float4*>(&E[h4 * 4 + 3][lane * 4]);
    const float4 dA = *reinterpret_cast<const float4*>(&decs[w][0][h4 * 4]);   // LDS broadcast
    const float4 dB = *reinterpret_cast<const float4*>(&decs[w][1][h4 * 4]);   // LDS broadcast
    const float4 v4 = *reinterpret_cast<const float4*>(&vts[h4 * 4]);          // LDS broadcast

    auto quad = [&v4](float ea, float eb, float ec, float ed, const float4& d, float& acc) {
      float t0 = fmaf(ea, d.x, 1.0f);
      float t1 = fmaf(eb, d.y, 1.0f);
      float t2 = fmaf(ec, d.z, 1.0f);
      float t3 = fmaf(ed, d.w, 1.0f);
      float t01 = t0 * t1;
      float t23 = t2 * t3;
      float n01 = fmaf(v4.x, t1, v4.y * t0);
      float n23 = fmaf(v4.z, t3, v4.w * t2);
      float den = t01 * t23;
      float num = fmaf(n01, t23, n23 * t01);
      acc = fmaf(num, __builtin_amdgcn_rcpf(den), acc);
    };
    quad(e0.x, e1.x, e2.x, e3.x, dA, aA0);
    quad(e0.y, e1.y, e2.y, e3.y, dA, aA1);
    quad(e0.z, e1.z, e2.z, e3.z, dA, aA2);
    quad(e0.w, e1.w, e2.w, e3.w, dA, aA3);
    quad(e0.x, e1.x, e2.x, e3.x, dB, aB0);
    quad(e0.y, e1.y, e2.y, e3.y, dB, aB1);
    quad(e0.z, e1.z, e2.z, e3.z, dB, aB2);
    quad(e0.w, e1.w, e2.w, e3.w, dB, aB3);
  }

  // ---- mask + softmax + store (wave-uniform validity: both rows valid or both invalid) ----
  if (uA < U_) {
    const float negs = -103.6163291847321f * 10.0f;   // log(1e-45) * EXPLORATION_C
    const float vs10 = vsum_s * 10.0f;
    #pragma unroll
    for (int r = 0; r < 2; ++r) {
      const float b0 = r ? aB0 : aA0, b1 = r ? aB1 : aA1;
      const float b2 = r ? aB2 : aA2, b3 = r ? aB3 : aA3;
      const int   m0 = r ? mB0 : mA0, m1 = r ? mB1 : mA1;
      const int   m2 = r ? mB2 : mA2, m3 = r ? mB3 : mA3;
      float s0 = m0 ? fmaf(-20.0f, b0, vs10) : negs;
      float s1 = m1 ? fmaf(-20.0f, b1, vs10) : negs;
      float s2 = m2 ? fmaf(-20.0f, b2, vs10) : negs;
      float s3 = m3 ? fmaf(-20.0f, b3, vs10) : negs;
      float mx = fmaxf(fmaxf(s0, s1), fmaxf(s2, s3));
      #pragma unroll
      for (int off = 32; off > 0; off >>= 1) mx = fmaxf(mx, __shfl_xor(mx, off, 64));
      float p0 = __expf(s0 - mx);
      float p1 = __expf(s1 - mx);
      float p2 = __expf(s2 - mx);
      float p3 = __expf(s3 - mx);
      float sum = (p0 + p1) + (p2 + p3);
      #pragma unroll
      for (int off = 32; off > 0; off >>= 1) sum += __shfl_xor(sum, off, 64);
      const float inv = __builtin_amdgcn_rcpf(sum);
      float4 o;
      o.x = p0 * inv; o.y = p1 * inv; o.z = p2 * inv; o.w = p3 * inv;
      *reinterpret_cast<float4*>(out + (r ? ridxB : ridxA)) = o;
    }
  }
}

extern "C" void kernel_launch(void* const* d_in, const int* in_sizes, int n_in,
                              void* d_out, int out_size, void* d_ws, size_t ws_size,
                              hipStream_t stream) {
  const float* user   = (const float*)d_in[0];
  const float* server = (const float*)d_in[1];
  const int*   masks  = (const int*)d_in[2];
  const float* Wu = (const float*)d_in[3];
  const float* bu = (const float*)d_in[4];
  const float* Ws = (const float*)d_in[5];
  const float* bs = (const float*)d_in[6];
  const float* W1 = (const float*)d_in[7];
  const float* W2 = (const float*)d_in[8];
  const float* vt = (const float*)d_in[9];
  float* out = (float*)d_out;
  (void)in_sizes; (void)n_in; (void)out_size; (void)d_ws; (void)ws_size;

  attn_kernel<<<dim3(B_ * ((U_ + UTILE - 1) / UTILE)), dim3(TPB), 0, stream>>>(
      user, server, masks, Wu, bu, Ws, bs, W1, W2, vt, out);
}